// Round 11
// baseline (281.053 us; speedup 1.0000x reference)
//
#include <hip/hip_runtime.h>
#include <hip/hip_bf16.h>

// Bahdanau attention, B=32 S=2048 H=1024, fp32 in/out.
// v11: k_scores11 = v10 (2-barrier BK=64, A+B global_load_lds, 32x32x16 MFMA)
// with corrected swizzle swz(r)=((r&7)+4*((r>>3)&1))&7: every 16-lane quarter
// hits each of the 8 slots exactly twice (2-way = free) for the 32-wide
// fragment rows. Staging inverse is chunk-invariant (swz(r+32)=swz(r)).
// convert/softmax/ctx unchanged (HBM floor). Fallback v1 path if ws small.

#define BB 32
#define SS 2048
#define HH 1024

typedef float  f32x4   __attribute__((ext_vector_type(4)));
typedef float  f32x16  __attribute__((ext_vector_type(16)));
typedef __bf16 bf16x4  __attribute__((ext_vector_type(4)));
typedef __bf16 bf16x8  __attribute__((ext_vector_type(8)));

__device__ inline __bf16 f2bf(float f) {
  unsigned u = __builtin_bit_cast(unsigned, f);
  u = (u + 0x7FFFu + ((u >> 16) & 1u)) >> 16;   // RNE (inputs are finite)
  unsigned short s = (unsigned short)u;
  return __builtin_bit_cast(__bf16, s);
}

__device__ inline float bf2f(__bf16 b) {
  unsigned short s = __builtin_bit_cast(unsigned short, b);
  unsigned u = ((unsigned)s) << 16;
  return __builtin_bit_cast(float, u);
}

__device__ inline float tanh_fast(float x) {
  x = fminf(fmaxf(x, -15.f), 15.f);
  float e = __expf(2.f * x);
  return (e - 1.f) / (e + 1.f);
}

__device__ __forceinline__ void gload16(const __bf16* g, __bf16* l) {
  __builtin_amdgcn_global_load_lds(
      (const __attribute__((address_space(1))) void*)g,
      (__attribute__((address_space(3))) void*)l, 16, 0, 0);
}

// ---- keys f32 -> bf16 (row-major) ----
__global__ void k_convert_keys(const float* __restrict__ src, __bf16* __restrict__ dst) {
  size_t i = ((size_t)blockIdx.x * 256 + threadIdx.x) * 8;
  f32x4 a = *(const f32x4*)(src + i);
  f32x4 b = *(const f32x4*)(src + i + 4);
  bf16x8 o;
  o[0] = f2bf(a[0]); o[1] = f2bf(a[1]); o[2] = f2bf(a[2]); o[3] = f2bf(a[3]);
  o[4] = f2bf(b[0]); o[5] = f2bf(b[1]); o[6] = f2bf(b[2]); o[7] = f2bf(b[3]);
  *(bf16x8*)(dst + i) = o;
}

// ---- Ua f32 -> bf16 (row-major) ----
__global__ void k_convert_ua(const float* __restrict__ src, __bf16* __restrict__ dst) {
  size_t i = (size_t)blockIdx.x * 256 + threadIdx.x;   // x4 elements
  f32x4 v = ((const f32x4*)src)[i];
  bf16x4 o;
  o[0] = f2bf(v[0]); o[1] = f2bf(v[1]); o[2] = f2bf(v[2]); o[3] = f2bf(v[3]);
  *(bf16x4*)(dst + i * 4) = o;
}

// ---- qpc[b][o] = dot(query[b], Wa[o]) + Wa_b[o] + Ua_b[o] ----
__global__ void k_qproj(const float* __restrict__ q, const float* __restrict__ wa,
                        const float* __restrict__ wab, const float* __restrict__ uab,
                        float* __restrict__ qpc) {
  int tid = threadIdx.x;
  int gid = blockIdx.x * 32 + (tid >> 3);
  int lane8 = tid & 7;
  int b = gid >> 10, o = gid & 1023;
  const f32x4* qv = (const f32x4*)(q + (size_t)b * HH);
  const f32x4* wv = (const f32x4*)(wa + (size_t)o * HH);
  float s = 0.f;
#pragma unroll 4
  for (int kk = lane8; kk < HH / 4; kk += 8) {
    f32x4 a = qv[kk], w = wv[kk];
    s += a[0] * w[0] + a[1] * w[1] + a[2] * w[2] + a[3] * w[3];
  }
  s += __shfl_xor(s, 1); s += __shfl_xor(s, 2); s += __shfl_xor(s, 4);
  if (lane8 == 0) qpc[(size_t)b * HH + o] = s + wab[o] + uab[o];
}

// ---- fused GEMM (32x32x16 MFMA) + tanh + Va -> per-o-tile score partials ----
// grid 4096 = 512 m-tiles x 8 o-tiles; m%8==blockIdx%8 keeps all 8 o-tiles
// of an m-tile on one XCD (A panel + Ua L2-resident).
// BK=64, single-buffered 2-barrier loop (16 iters).
// Swizzle: LDS 16B-slot s of row r holds global k-octet (s - swz(r))&7 with
// swz(r) = ((r&7) + 4*((r>>3)&1))&7. Reads: slot (g + swz(r))&7 -> each
// 16-lane quarter hits each slot exactly 2x (2-way = free).
__global__ void __launch_bounds__(256) k_scores11(
    const __bf16* __restrict__ keysb, const __bf16* __restrict__ ua,
    const float* __restrict__ qpc, const float* __restrict__ vaw,
    float* __restrict__ spart) {
  __shared__ __align__(16) __bf16 Alds[128 * 64];   // 16 KB, swizzled
  __shared__ __align__(16) __bf16 Blds[128 * 64];   // 16 KB, swizzled
  __shared__ float scorebuf[128];

  int raw = blockIdx.x;
  int o = (raw >> 3) & 7;
  int m = ((raw >> 6) << 3) | (raw & 7);
  int b = m >> 4;
  long grow0 = (long)m * 128;
  int o0 = o * 128;

  int tid = threadIdx.x;
  int w = tid >> 6, lane = tid & 63;
  int wm = w >> 1, wn = w & 1;          // 2x2 waves, 64x64 each
  int l31 = lane & 31, hi2 = lane >> 5; // 32x32 fragment coords

  // ---- staging: chunk p covers rows [p*32,+32); thread -> row p*32+(tid>>3),
  // LDS slot tid&7. swz is invariant under r+32, so one source offset for all
  // chunks: global slot g = (sslot - swz(srow))&7.
  int srow = tid >> 3;
  int sslot = tid & 7;
  int g = (sslot - ((srow & 7) + 4 * ((srow >> 3) & 1))) & 7;
  const __bf16* ag0 = keysb + (size_t)(grow0 + srow) * HH + g * 8;
  const __bf16* ag1 = ag0 + (size_t)32 * HH;
  const __bf16* ag2 = ag0 + (size_t)64 * HH;
  const __bf16* ag3 = ag0 + (size_t)96 * HH;
  const __bf16* bg0 = ua + (size_t)(o0 + srow) * HH + g * 8;
  const __bf16* bg1 = bg0 + (size_t)32 * HH;
  const __bf16* bg2 = bg0 + (size_t)64 * HH;
  const __bf16* bg3 = bg0 + (size_t)96 * HH;
  __bf16* al0 = Alds + 0 * 2048 + w * 512;   // wave-uniform dests
  __bf16* al1 = Alds + 1 * 2048 + w * 512;
  __bf16* al2 = Alds + 2 * 2048 + w * 512;
  __bf16* al3 = Alds + 3 * 2048 + w * 512;
  __bf16* bl0 = Blds + 0 * 2048 + w * 512;
  __bf16* bl1 = Blds + 1 * 2048 + w * 512;
  __bf16* bl2 = Blds + 2 * 2048 + w * 512;
  __bf16* bl3 = Blds + 3 * 2048 + w * 512;

  // ---- fragment reads (32x32x16): row = base + l31 (base mult of 32) ->
  // swz(row) = swz(l31); k-octet g = ks*2 + hi2 -> slot (g + swz)&7.
  int swzr = ((l31 & 7) + 4 * ((l31 >> 3) & 1)) & 7;
  int ra = (wm * 64 + l31) * 64;        // + mi*32*64
  int rb = (wn * 64 + l31) * 64;        // + ni*32*64

  f32x16 acc[2][2] = {};

  for (int kt = 0; kt < 16; ++kt) {     // K = 1024, BK = 64
    if (kt) __syncthreads();            // prev iter's frag reads done
    int ko = kt * 64;
    gload16(ag0 + ko, al0); gload16(ag1 + ko, al1);
    gload16(ag2 + ko, al2); gload16(ag3 + ko, al3);
    gload16(bg0 + ko, bl0); gload16(bg1 + ko, bl1);
    gload16(bg2 + ko, bl2); gload16(bg3 + ko, bl3);
    __syncthreads();                    // vmcnt(0) drain: tile landed

#pragma unroll
    for (int ks = 0; ks < 4; ++ks) {
      int so = ((ks * 2 + hi2 + swzr) & 7) * 8;   // swizzled 16B slot offset
      bf16x8 a0 = *(const bf16x8*)(Alds + ra + so);
      bf16x8 a1 = *(const bf16x8*)(Alds + ra + 2048 + so);
      bf16x8 b0 = *(const bf16x8*)(Blds + rb + so);
      bf16x8 b1 = *(const bf16x8*)(Blds + rb + 2048 + so);
      acc[0][0] = __builtin_amdgcn_mfma_f32_32x32x16_bf16(a0, b0, acc[0][0], 0, 0, 0);
      acc[0][1] = __builtin_amdgcn_mfma_f32_32x32x16_bf16(a0, b1, acc[0][1], 0, 0, 0);
      acc[1][0] = __builtin_amdgcn_mfma_f32_32x32x16_bf16(a1, b0, acc[1][0], 0, 0, 0);
      acc[1][1] = __builtin_amdgcn_mfma_f32_32x32x16_bf16(a1, b1, acc[1][1], 0, 0, 0);
    }
  }

  // ---- epilogue: C layout col = l31, row = (reg&3)+8*(reg>>2)+4*hi2.
  float qv0, qv1, vv0, vv1;
  {
    int oc0 = o0 + wn * 64 + l31;
    int oc1 = oc0 + 32;
    qv0 = qpc[(size_t)b * HH + oc0]; vv0 = vaw[oc0];
    qv1 = qpc[(size_t)b * HH + oc1]; vv1 = vaw[oc1];
  }
#pragma unroll
  for (int mi = 0; mi < 2; ++mi)
#pragma unroll
    for (int reg = 0; reg < 16; ++reg) {
      float v = tanh_fast(acc[mi][0][reg] + qv0) * vv0 +
                tanh_fast(acc[mi][1][reg] + qv1) * vv1;
      v += __shfl_xor(v, 1); v += __shfl_xor(v, 2); v += __shfl_xor(v, 4);
      v += __shfl_xor(v, 8); v += __shfl_xor(v, 16);   // sum over 32 cols
      acc[mi][0][reg] = v;               // stash row-sum (no extra VGPR)
    }
  if (wn == 1 && l31 == 0) {
#pragma unroll
    for (int mi = 0; mi < 2; ++mi)
#pragma unroll
      for (int reg = 0; reg < 16; ++reg) {
        int rrow = wm * 64 + mi * 32 + (reg & 3) + 8 * (reg >> 2) + 4 * hi2;
        scorebuf[rrow] = acc[mi][0][reg];
      }
  }
  __syncthreads();
  if (wn == 0 && l31 == 0) {
#pragma unroll
    for (int mi = 0; mi < 2; ++mi)
#pragma unroll
      for (int reg = 0; reg < 16; ++reg) {
        int rrow = wm * 64 + mi * 32 + (reg & 3) + 8 * (reg >> 2) + 4 * hi2;
        spart[(size_t)o * (BB * SS) + grow0 + rrow] = acc[mi][0][reg] + scorebuf[rrow];
      }
  }
}

// ---- v1 fused-conversion GEMM (fallback when ws is small) ----
__global__ void __launch_bounds__(256) k_scores_fused(
    const float* __restrict__ keys, const __bf16* __restrict__ ua,
    const float* __restrict__ qpc, const float* __restrict__ vaw,
    float* __restrict__ spart) {
  __shared__ __bf16 Alds[128][40];
  __shared__ float scorebuf[128];

  int raw = blockIdx.x;
  int o = (raw >> 3) & 7;
  int m = ((raw >> 6) << 3) | (raw & 7);
  int b = m >> 4;
  long grow0 = (long)m * 128;
  int o0 = o * 128;

  int tid = threadIdx.x;
  int w = tid >> 6, lane = tid & 63;
  int wm = w >> 1, wn = w & 1;
  int ln = lane & 15, hi = lane >> 4;

  int srow = tid >> 3;
  int sk4 = tid & 7;
  const f32x4* keysv = (const f32x4*)keys;
  const bf16x8* uav = (const bf16x8*)ua;

  f32x4 acc[4][4] = {};

  for (int kt = 0; kt < 32; ++kt) {
    int k0 = kt * 32;
    bf16x8 bf[4];
#pragma unroll
    for (int ni = 0; ni < 4; ++ni) {
      int oc = o0 + wn * 64 + ni * 16 + ln;
      bf[ni] = uav[(size_t)oc * (HH / 8) + (k0 >> 3) + hi];
    }
    f32x4 st[4];
#pragma unroll
    for (int p = 0; p < 4; ++p)
      st[p] = keysv[((size_t)(grow0 + srow + 32 * p) << 8) + (size_t)(kt * 8 + sk4)];
    __syncthreads();
#pragma unroll
    for (int p = 0; p < 4; ++p) {
      bf16x4 t;
      t[0] = f2bf(st[p][0]); t[1] = f2bf(st[p][1]);
      t[2] = f2bf(st[p][2]); t[3] = f2bf(st[p][3]);
      *(bf16x4*)&Alds[srow + 32 * p][sk4 * 4] = t;
    }
    __syncthreads();
    bf16x8 af[4];
#pragma unroll
    for (int mi = 0; mi < 4; ++mi)
      af[mi] = *(const bf16x8*)&Alds[wm * 64 + mi * 16 + ln][hi * 8];
#pragma unroll
    for (int mi = 0; mi < 4; ++mi)
#pragma unroll
      for (int ni = 0; ni < 4; ++ni)
        acc[mi][ni] = __builtin_amdgcn_mfma_f32_16x16x32_bf16(af[mi], bf[ni], acc[mi][ni], 0, 0, 0);
  }

  float qv[4], vv[4];
#pragma unroll
  for (int ni = 0; ni < 4; ++ni) {
    int oc = o0 + wn * 64 + ni * 16 + ln;
    qv[ni] = qpc[(size_t)b * HH + oc];
    vv[ni] = vaw[oc];
  }
  float rsum[4][4];
#pragma unroll
  for (int mi = 0; mi < 4; ++mi)
#pragma unroll
    for (int j = 0; j < 4; ++j) {
      float v = 0.f;
#pragma unroll
      for (int ni = 0; ni < 4; ++ni)
        v += tanh_fast(acc[mi][ni][j] + qv[ni]) * vv[ni];
      v += __shfl_xor(v, 1); v += __shfl_xor(v, 2);
      v += __shfl_xor(v, 4); v += __shfl_xor(v, 8);
      rsum[mi][j] = v;
    }
  if (wn == 1 && ln == 0) {
#pragma unroll
    for (int mi = 0; mi < 4; ++mi)
#pragma unroll
      for (int j = 0; j < 4; ++j)
        scorebuf[wm * 64 + mi * 16 + hi * 4 + j] = rsum[mi][j];
  }
  __syncthreads();
  if (wn == 0 && ln == 0) {
#pragma unroll
    for (int mi = 0; mi < 4; ++mi)
#pragma unroll
      for (int j = 0; j < 4; ++j) {
        int rl = wm * 64 + mi * 16 + hi * 4 + j;
        spart[(size_t)o * (BB * SS) + grow0 + rl] = rsum[mi][j] + scorebuf[rl];
      }
  }
}

// ---- softmax over S per batch (Va_b cancels) ----
__global__ void k_softmax(const float* __restrict__ spart, float* __restrict__ wout) {
  int b = blockIdx.x, tid = threadIdx.x;
  __shared__ float red[8];
  int w = tid >> 6;
  float sc[8];
  float mx = -1e30f;
#pragma unroll
  for (int i = 0; i < 8; ++i) {
    int s = tid + i * 256;
    float v = 0.f;
#pragma unroll
    for (int ot = 0; ot < 8; ++ot) v += spart[(size_t)ot * (BB * SS) + b * SS + s];
    sc[i] = v; mx = fmaxf(mx, v);
  }
#pragma unroll
  for (int off = 1; off < 64; off <<= 1) mx = fmaxf(mx, __shfl_xor(mx, off));
  if ((tid & 63) == 0) red[w] = mx;
  __syncthreads();
  mx = fmaxf(fmaxf(red[0], red[1]), fmaxf(red[2], red[3]));
  float sum = 0.f;
#pragma unroll
  for (int i = 0; i < 8; ++i) { sc[i] = __expf(sc[i] - mx); sum += sc[i]; }
#pragma unroll
  for (int off = 1; off < 64; off <<= 1) sum += __shfl_xor(sum, off);
  if ((tid & 63) == 0) red[4 + w] = sum;
  __syncthreads();
  sum = (red[4] + red[5]) + (red[6] + red[7]);
  float inv = 1.f / sum;
#pragma unroll
  for (int i = 0; i < 8; ++i) wout[(size_t)b * SS + tid + i * 256] = sc[i] * inv;
}

// ---- context partials from bf16 keys: 512 blocks = 32 b x 16 s-chunks ----
__global__ void k_ctx_part_bf(const __bf16* __restrict__ keysb, const float* __restrict__ wts,
                              float* __restrict__ cpart) {
  int bc = blockIdx.x;
  int b = bc >> 4, sc = bc & 15;
  int tid = threadIdx.x;
  int s0 = sc * 128;
  f32x4 a0 = {0,0,0,0}, a1 = {0,0,0,0}, a2 = {0,0,0,0}, a3 = {0,0,0,0};
  for (int s = 0; s < 128; s += 4) {
    size_t base = (size_t)b * SS + s0 + s;
    float w0 = wts[base + 0], w1 = wts[base + 1], w2 = wts[base + 2], w3 = wts[base + 3];
    bf16x4 k0 = *(const bf16x4*)(keysb + (base + 0) * HH + tid * 4);
    bf16x4 k1 = *(const bf16x4*)(keysb + (base + 1) * HH + tid * 4);
    bf16x4 k2 = *(const bf16x4*)(keysb + (base + 2) * HH + tid * 4);
    bf16x4 k3 = *(const bf16x4*)(keysb + (base + 3) * HH + tid * 4);
#pragma unroll
    for (int j = 0; j < 4; ++j) {
      a0[j] += w0 * bf2f(k0[j]);
      a1[j] += w1 * bf2f(k1[j]);
      a2[j] += w2 * bf2f(k2[j]);
      a3[j] += w3 * bf2f(k3[j]);
    }
  }
  f32x4 a = (a0 + a1) + (a2 + a3);
  ((f32x4*)cpart)[(size_t)bc * (HH / 4) + tid] = a;
}

// ---- fp32-keys context partial (fallback path) ----
__global__ void k_ctx_part(const float* __restrict__ keys, const float* __restrict__ wts,
                           float* __restrict__ cpart) {
  int bc = blockIdx.x;
  int b = bc >> 4, sc = bc & 15;
  int tid = threadIdx.x;
  int s0 = sc * 128;
  const f32x4* kv = (const f32x4*)keys;
  f32x4 a0 = {0,0,0,0}, a1 = {0,0,0,0}, a2 = {0,0,0,0}, a3 = {0,0,0,0};
  for (int s = 0; s < 128; s += 4) {
    size_t base = (size_t)b * SS + s0 + s;
    a0 += wts[base + 0] * kv[(base + 0) * (HH / 4) + tid];
    a1 += wts[base + 1] * kv[(base + 1) * (HH / 4) + tid];
    a2 += wts[base + 2] * kv[(base + 2) * (HH / 4) + tid];
    a3 += wts[base + 3] * kv[(base + 3) * (HH / 4) + tid];
  }
  f32x4 a = (a0 + a1) + (a2 + a3);
  ((f32x4*)cpart)[(size_t)bc * (HH / 4) + tid] = a;
}

__global__ void k_ctx_red(const float* __restrict__ cpart, float* __restrict__ ctx) {
  int i = blockIdx.x * 256 + threadIdx.x;  // over B*H
  int b = i >> 10, h = i & 1023;
  float v = 0.f;
#pragma unroll
  for (int sc = 0; sc < 16; ++sc) v += cpart[((size_t)(b * 16 + sc)) * HH + h];
  ctx[i] = v;
}

extern "C" void kernel_launch(void* const* d_in, const int* in_sizes, int n_in,
                              void* d_out, int out_size, void* d_ws, size_t ws_size,
                              hipStream_t stream) {
  (void)in_sizes; (void)n_in; (void)out_size;
  const float* query = (const float*)d_in[0];
  const float* keys  = (const float*)d_in[1];
  const float* wa_w  = (const float*)d_in[2];
  const float* wa_b  = (const float*)d_in[3];
  const float* ua_w  = (const float*)d_in[4];
  const float* ua_b  = (const float*)d_in[5];
  const float* va_w  = (const float*)d_in[6];
  // va_b (d_in[7]) cancels in softmax

  char* ws = (char*)d_ws;
  float* ctx_out = (float*)d_out;            // [32][1024]
  float* w_out   = ctx_out + BB * HH;        // [32][2048]

  const size_t need = (size_t)135 << 20;
  if (ws_size >= need) {
    __bf16* keys_bf = (__bf16*)ws;                              // 128 MB
    __bf16* ua_bf   = (__bf16*)(ws + ((size_t)128 << 20));      // 2 MB
    float*  qpc     = (float*)(ws + ((size_t)130 << 20));       // 128 KB
    float*  spart   = (float*)(ws + ((size_t)131 << 20));       // 2 MB
    float*  cpart   = (float*)(ws + ((size_t)133 << 20));       // 2 MB

    k_convert_keys<<<BB * SS * HH / (256 * 8), 256, 0, stream>>>(keys, keys_bf);
    k_convert_ua<<<1024, 256, 0, stream>>>(ua_w, ua_bf);
    k_qproj<<<1024, 256, 0, stream>>>(query, wa_w, wa_b, ua_b, qpc);
    k_scores11<<<4096, 256, 0, stream>>>(keys_bf, ua_bf, qpc, va_w, spart);
    k_softmax<<<BB, 256, 0, stream>>>(spart, w_out);
    k_ctx_part_bf<<<512, 256, 0, stream>>>(keys_bf, w_out, cpart);
    k_ctx_red<<<BB * HH / 256, 256, 0, stream>>>(cpart, ctx_out);
  } else {
    __bf16* ua_bf  = (__bf16*)ws;                                    // 2 MB
    float*  qpc    = (float*)(ws + (2u << 20));                      // 128 KB
    float*  spart  = (float*)(ws + (2u << 20) + (128u << 10));       // 2 MB
    float*  cpart  = (float*)(ws + (4u << 20) + (128u << 10));       // 2 MB

    k_convert_ua<<<1024, 256, 0, stream>>>(ua_w, ua_bf);
    k_qproj<<<1024, 256, 0, stream>>>(query, wa_w, wa_b, ua_b, qpc);
    k_scores_fused<<<4096, 256, 0, stream>>>(keys, ua_bf, qpc, va_w, spart);
    k_softmax<<<BB, 256, 0, stream>>>(spart, w_out);
    k_ctx_part<<<512, 256, 0, stream>>>(keys, w_out, cpart);
    k_ctx_red<<<BB * HH / 256, 256, 0, stream>>>(cpart, ctx_out);
  }
}

// Round 12
// 256.790 us; speedup vs baseline: 1.0945x; 1.0945x over previous
//
#include <hip/hip_runtime.h>
#include <hip/hip_bf16.h>

// Bahdanau attention, B=32 S=2048 H=1024, fp32 in/out.
// v12 = v5 (best measured: 258 µs): k_scores5 = 2-barrier skeleton, A AND B
// staged via global_load_lds w16, swizzled LDS layout both operands
// (slot-permuted source, 0 bank conflicts), BK=64. ctx reads bf16 keys.
// Ledger: all 4 pipeline variants, B-from-global, fused-convert, and both
// 32x32-MFMA variants measured slower. Fallback v1 fused path if ws small.

#define BB 32
#define SS 2048
#define HH 1024

typedef float  f32x4  __attribute__((ext_vector_type(4)));
typedef __bf16 bf16x4 __attribute__((ext_vector_type(4)));
typedef __bf16 bf16x8 __attribute__((ext_vector_type(8)));

__device__ inline __bf16 f2bf(float f) {
  unsigned u = __builtin_bit_cast(unsigned, f);
  u = (u + 0x7FFFu + ((u >> 16) & 1u)) >> 16;   // RNE (inputs are finite)
  unsigned short s = (unsigned short)u;
  return __builtin_bit_cast(__bf16, s);
}

__device__ inline float bf2f(__bf16 b) {
  unsigned short s = __builtin_bit_cast(unsigned short, b);
  unsigned u = ((unsigned)s) << 16;
  return __builtin_bit_cast(float, u);
}

__device__ inline float tanh_fast(float x) {
  x = fminf(fmaxf(x, -15.f), 15.f);
  float e = __expf(2.f * x);
  return (e - 1.f) / (e + 1.f);
}

__device__ __forceinline__ void gload16(const __bf16* g, __bf16* l) {
  __builtin_amdgcn_global_load_lds(
      (const __attribute__((address_space(1))) void*)g,
      (__attribute__((address_space(3))) void*)l, 16, 0, 0);
}

// ---- keys f32 -> bf16 (row-major) ----
__global__ void k_convert_keys(const float* __restrict__ src, __bf16* __restrict__ dst) {
  size_t i = ((size_t)blockIdx.x * 256 + threadIdx.x) * 8;
  f32x4 a = *(const f32x4*)(src + i);
  f32x4 b = *(const f32x4*)(src + i + 4);
  bf16x8 o;
  o[0] = f2bf(a[0]); o[1] = f2bf(a[1]); o[2] = f2bf(a[2]); o[3] = f2bf(a[3]);
  o[4] = f2bf(b[0]); o[5] = f2bf(b[1]); o[6] = f2bf(b[2]); o[7] = f2bf(b[3]);
  *(bf16x8*)(dst + i) = o;
}

// ---- Ua f32 -> bf16 (row-major) ----
__global__ void k_convert_ua(const float* __restrict__ src, __bf16* __restrict__ dst) {
  size_t i = (size_t)blockIdx.x * 256 + threadIdx.x;   // x4 elements
  f32x4 v = ((const f32x4*)src)[i];
  bf16x4 o;
  o[0] = f2bf(v[0]); o[1] = f2bf(v[1]); o[2] = f2bf(v[2]); o[3] = f2bf(v[3]);
  *(bf16x4*)(dst + i * 4) = o;
}

// ---- qpc[b][o] = dot(query[b], Wa[o]) + Wa_b[o] + Ua_b[o] ----
__global__ void k_qproj(const float* __restrict__ q, const float* __restrict__ wa,
                        const float* __restrict__ wab, const float* __restrict__ uab,
                        float* __restrict__ qpc) {
  int tid = threadIdx.x;
  int gid = blockIdx.x * 32 + (tid >> 3);
  int lane8 = tid & 7;
  int b = gid >> 10, o = gid & 1023;
  const f32x4* qv = (const f32x4*)(q + (size_t)b * HH);
  const f32x4* wv = (const f32x4*)(wa + (size_t)o * HH);
  float s = 0.f;
#pragma unroll 4
  for (int kk = lane8; kk < HH / 4; kk += 8) {
    f32x4 a = qv[kk], w = wv[kk];
    s += a[0] * w[0] + a[1] * w[1] + a[2] * w[2] + a[3] * w[3];
  }
  s += __shfl_xor(s, 1); s += __shfl_xor(s, 2); s += __shfl_xor(s, 4);
  if (lane8 == 0) qpc[(size_t)b * HH + o] = s + wab[o] + uab[o];
}

// ---- fused GEMM + tanh + Va -> per-o-tile score partials ----
// grid 4096 = 512 m-tiles x 8 o-tiles; m%8==blockIdx%8 keeps all 8 o-tiles of
// an m-tile on one XCD (A panel + Ua L2-resident).
// BK=64, single-buffered 2-barrier loop (16 iters). Swizzled LDS layout for
// BOTH operands: LDS[r][s] = G[r][(s-r)&7] (16B slots, 8/row) -> staging via
// inverse-permuted global source (linear gload_lds dest), reads at slot
// (g+r)&7 -> conflict-free ds_read_b128.
__global__ void __launch_bounds__(256) k_scores5(
    const __bf16* __restrict__ keysb, const __bf16* __restrict__ ua,
    const float* __restrict__ qpc, const float* __restrict__ vaw,
    float* __restrict__ spart) {
  __shared__ __align__(16) __bf16 Alds[128 * 64];   // 16 KB, swizzled
  __shared__ __align__(16) __bf16 Blds[128 * 64];   // 16 KB, swizzled
  __shared__ float scorebuf[128];

  int raw = blockIdx.x;
  int o = (raw >> 3) & 7;
  int m = ((raw >> 6) << 3) | (raw & 7);
  int b = m >> 4;
  long grow0 = (long)m * 128;
  int o0 = o * 128;

  int tid = threadIdx.x;
  int w = tid >> 6, lane = tid & 63;
  int wm = w >> 1, wn = w & 1;          // 2x2 waves, 64x64 each
  int ln = lane & 15, hi = lane >> 4;

  // staging: chunk p covers rows [p*32, p*32+32); thread -> row p*32+(tid>>3),
  // LDS slot tid&7, global slot (slot-row)&7 (inverse of read swizzle)
  int srow = tid >> 3;
  int sslot = tid & 7;
  const __bf16 *ag0, *ag1, *ag2, *ag3, *bg0, *bg1, *bg2, *bg3;
  {
    int r0 = 0 * 32 + srow, r1 = 1 * 32 + srow, r2 = 2 * 32 + srow, r3 = 3 * 32 + srow;
    int g0 = (sslot - r0) & 7, g1 = (sslot - r1) & 7, g2 = (sslot - r2) & 7, g3 = (sslot - r3) & 7;
    ag0 = keysb + (size_t)(grow0 + r0) * HH + g0 * 8;
    ag1 = keysb + (size_t)(grow0 + r1) * HH + g1 * 8;
    ag2 = keysb + (size_t)(grow0 + r2) * HH + g2 * 8;
    ag3 = keysb + (size_t)(grow0 + r3) * HH + g3 * 8;
    bg0 = ua + (size_t)(o0 + r0) * HH + g0 * 8;
    bg1 = ua + (size_t)(o0 + r1) * HH + g1 * 8;
    bg2 = ua + (size_t)(o0 + r2) * HH + g2 * 8;
    bg3 = ua + (size_t)(o0 + r3) * HH + g3 * 8;
  }
  __bf16* al0 = Alds + 0 * 2048 + w * 512;   // wave-uniform dests
  __bf16* al1 = Alds + 1 * 2048 + w * 512;
  __bf16* al2 = Alds + 2 * 2048 + w * 512;
  __bf16* al3 = Alds + 3 * 2048 + w * 512;
  __bf16* bl0 = Blds + 0 * 2048 + w * 512;
  __bf16* bl1 = Blds + 1 * 2048 + w * 512;
  __bf16* bl2 = Blds + 2 * 2048 + w * 512;
  __bf16* bl3 = Blds + 3 * 2048 + w * 512;

  // fragment reads: row r, global slot g=kk*4+hi -> LDS slot (g+r)&7;
  // r mod 8 == ln&7, so slot = (kk*4+hi+ln)&7 independent of mi/ni.
  int ra = (wm * 64 + ln) * 64;         // + mi*1024
  int rb = (wn * 64 + ln) * 64;         // + ni*1024
  int sa0 = ((hi + ln) & 7) * 8;        // kk=0 slot offset (elems)
  int sa1 = ((4 + hi + ln) & 7) * 8;    // kk=1

  f32x4 acc[4][4] = {};

  for (int kt = 0; kt < 16; ++kt) {     // K = 1024, BK = 64
    if (kt) __syncthreads();            // prev iter's frag reads done
    int ko = kt * 64;
    gload16(ag0 + ko, al0); gload16(ag1 + ko, al1);
    gload16(ag2 + ko, al2); gload16(ag3 + ko, al3);
    gload16(bg0 + ko, bl0); gload16(bg1 + ko, bl1);
    gload16(bg2 + ko, bl2); gload16(bg3 + ko, bl3);
    __syncthreads();                    // vmcnt(0) drain: tile landed

    bf16x8 af[4], bfr[4];
    // k-half 0
#pragma unroll
    for (int mi = 0; mi < 4; ++mi)
      af[mi] = *(const bf16x8*)(Alds + ra + mi * 1024 + sa0);
#pragma unroll
    for (int ni = 0; ni < 4; ++ni)
      bfr[ni] = *(const bf16x8*)(Blds + rb + ni * 1024 + sa0);
#pragma unroll
    for (int mi = 0; mi < 4; ++mi)
#pragma unroll
      for (int ni = 0; ni < 4; ++ni)
        acc[mi][ni] = __builtin_amdgcn_mfma_f32_16x16x32_bf16(af[mi], bfr[ni], acc[mi][ni], 0, 0, 0);
    // k-half 1
#pragma unroll
    for (int mi = 0; mi < 4; ++mi)
      af[mi] = *(const bf16x8*)(Alds + ra + mi * 1024 + sa1);
#pragma unroll
    for (int ni = 0; ni < 4; ++ni)
      bfr[ni] = *(const bf16x8*)(Blds + rb + ni * 1024 + sa1);
#pragma unroll
    for (int mi = 0; mi < 4; ++mi)
#pragma unroll
      for (int ni = 0; ni < 4; ++ni)
        acc[mi][ni] = __builtin_amdgcn_mfma_f32_16x16x32_bf16(af[mi], bfr[ni], acc[mi][ni], 0, 0, 0);
  }

  // epilogue: score partial = sum over this block's 128 o-cols of tanh(kp+qpc)*va
  float qv[4], vv[4];
#pragma unroll
  for (int ni = 0; ni < 4; ++ni) {
    int oc = o0 + wn * 64 + ni * 16 + ln;
    qv[ni] = qpc[(size_t)b * HH + oc];
    vv[ni] = vaw[oc];
  }
  float rsum[4][4];
#pragma unroll
  for (int mi = 0; mi < 4; ++mi)
#pragma unroll
    for (int j = 0; j < 4; ++j) {
      float v = 0.f;
#pragma unroll
      for (int ni = 0; ni < 4; ++ni)
        v += tanh_fast(acc[mi][ni][j] + qv[ni]) * vv[ni];
      v += __shfl_xor(v, 1); v += __shfl_xor(v, 2);
      v += __shfl_xor(v, 4); v += __shfl_xor(v, 8);   // sum over 16 cols (ln)
      rsum[mi][j] = v;
    }
  if (wn == 1 && ln == 0) {
#pragma unroll
    for (int mi = 0; mi < 4; ++mi)
#pragma unroll
      for (int j = 0; j < 4; ++j)
        scorebuf[wm * 64 + mi * 16 + hi * 4 + j] = rsum[mi][j];
  }
  __syncthreads();
  if (wn == 0 && ln == 0) {
#pragma unroll
    for (int mi = 0; mi < 4; ++mi)
#pragma unroll
      for (int j = 0; j < 4; ++j) {
        int rl = wm * 64 + mi * 16 + hi * 4 + j;
        spart[(size_t)o * (BB * SS) + grow0 + rl] = rsum[mi][j] + scorebuf[rl];
      }
  }
}

// ---- v1 fused-conversion GEMM (fallback when ws is small) ----
__global__ void __launch_bounds__(256) k_scores_fused(
    const float* __restrict__ keys, const __bf16* __restrict__ ua,
    const float* __restrict__ qpc, const float* __restrict__ vaw,
    float* __restrict__ spart) {
  __shared__ __bf16 Alds[128][40];
  __shared__ float scorebuf[128];

  int raw = blockIdx.x;
  int o = (raw >> 3) & 7;
  int m = ((raw >> 6) << 3) | (raw & 7);
  int b = m >> 4;
  long grow0 = (long)m * 128;
  int o0 = o * 128;

  int tid = threadIdx.x;
  int w = tid >> 6, lane = tid & 63;
  int wm = w >> 1, wn = w & 1;
  int ln = lane & 15, hi = lane >> 4;

  int srow = tid >> 3;
  int sk4 = tid & 7;
  const f32x4* keysv = (const f32x4*)keys;
  const bf16x8* uav = (const bf16x8*)ua;

  f32x4 acc[4][4] = {};

  for (int kt = 0; kt < 32; ++kt) {
    int k0 = kt * 32;
    bf16x8 bf[4];
#pragma unroll
    for (int ni = 0; ni < 4; ++ni) {
      int oc = o0 + wn * 64 + ni * 16 + ln;
      bf[ni] = uav[(size_t)oc * (HH / 8) + (k0 >> 3) + hi];
    }
    f32x4 st[4];
#pragma unroll
    for (int p = 0; p < 4; ++p)
      st[p] = keysv[((size_t)(grow0 + srow + 32 * p) << 8) + (size_t)(kt * 8 + sk4)];
    __syncthreads();
#pragma unroll
    for (int p = 0; p < 4; ++p) {
      bf16x4 t;
      t[0] = f2bf(st[p][0]); t[1] = f2bf(st[p][1]);
      t[2] = f2bf(st[p][2]); t[3] = f2bf(st[p][3]);
      *(bf16x4*)&Alds[srow + 32 * p][sk4 * 4] = t;
    }
    __syncthreads();
    bf16x8 af[4];
#pragma unroll
    for (int mi = 0; mi < 4; ++mi)
      af[mi] = *(const bf16x8*)&Alds[wm * 64 + mi * 16 + ln][hi * 8];
#pragma unroll
    for (int mi = 0; mi < 4; ++mi)
#pragma unroll
      for (int ni = 0; ni < 4; ++ni)
        acc[mi][ni] = __builtin_amdgcn_mfma_f32_16x16x32_bf16(af[mi], bf[ni], acc[mi][ni], 0, 0, 0);
  }

  float qv[4], vv[4];
#pragma unroll
  for (int ni = 0; ni < 4; ++ni) {
    int oc = o0 + wn * 64 + ni * 16 + ln;
    qv[ni] = qpc[(size_t)b * HH + oc];
    vv[ni] = vaw[oc];
  }
  float rsum[4][4];
#pragma unroll
  for (int mi = 0; mi < 4; ++mi)
#pragma unroll
    for (int j = 0; j < 4; ++j) {
      float v = 0.f;
#pragma unroll
      for (int ni = 0; ni < 4; ++ni)
        v += tanh_fast(acc[mi][ni][j] + qv[ni]) * vv[ni];
      v += __shfl_xor(v, 1); v += __shfl_xor(v, 2);
      v += __shfl_xor(v, 4); v += __shfl_xor(v, 8);
      rsum[mi][j] = v;
    }
  if (wn == 1 && ln == 0) {
#pragma unroll
    for (int mi = 0; mi < 4; ++mi)
#pragma unroll
      for (int j = 0; j < 4; ++j)
        scorebuf[wm * 64 + mi * 16 + hi * 4 + j] = rsum[mi][j];
  }
  __syncthreads();
  if (wn == 0 && ln == 0) {
#pragma unroll
    for (int mi = 0; mi < 4; ++mi)
#pragma unroll
      for (int j = 0; j < 4; ++j) {
        int rl = wm * 64 + mi * 16 + hi * 4 + j;
        spart[(size_t)o * (BB * SS) + grow0 + rl] = rsum[mi][j] + scorebuf[rl];
      }
  }
}

// ---- softmax over S per batch (Va_b cancels) ----
__global__ void k_softmax(const float* __restrict__ spart, float* __restrict__ wout) {
  int b = blockIdx.x, tid = threadIdx.x;
  __shared__ float red[8];
  int w = tid >> 6;
  float sc[8];
  float mx = -1e30f;
#pragma unroll
  for (int i = 0; i < 8; ++i) {
    int s = tid + i * 256;
    float v = 0.f;
#pragma unroll
    for (int ot = 0; ot < 8; ++ot) v += spart[(size_t)ot * (BB * SS) + b * SS + s];
    sc[i] = v; mx = fmaxf(mx, v);
  }
#pragma unroll
  for (int off = 1; off < 64; off <<= 1) mx = fmaxf(mx, __shfl_xor(mx, off));
  if ((tid & 63) == 0) red[w] = mx;
  __syncthreads();
  mx = fmaxf(fmaxf(red[0], red[1]), fmaxf(red[2], red[3]));
  float sum = 0.f;
#pragma unroll
  for (int i = 0; i < 8; ++i) { sc[i] = __expf(sc[i] - mx); sum += sc[i]; }
#pragma unroll
  for (int off = 1; off < 64; off <<= 1) sum += __shfl_xor(sum, off);
  if ((tid & 63) == 0) red[4 + w] = sum;
  __syncthreads();
  sum = (red[4] + red[5]) + (red[6] + red[7]);
  float inv = 1.f / sum;
#pragma unroll
  for (int i = 0; i < 8; ++i) wout[(size_t)b * SS + tid + i * 256] = sc[i] * inv;
}

// ---- context partials from bf16 keys: 512 blocks = 32 b x 16 s-chunks ----
__global__ void k_ctx_part_bf(const __bf16* __restrict__ keysb, const float* __restrict__ wts,
                              float* __restrict__ cpart) {
  int bc = blockIdx.x;
  int b = bc >> 4, sc = bc & 15;
  int tid = threadIdx.x;
  int s0 = sc * 128;
  f32x4 a0 = {0,0,0,0}, a1 = {0,0,0,0}, a2 = {0,0,0,0}, a3 = {0,0,0,0};
  for (int s = 0; s < 128; s += 4) {
    size_t base = (size_t)b * SS + s0 + s;
    float w0 = wts[base + 0], w1 = wts[base + 1], w2 = wts[base + 2], w3 = wts[base + 3];
    bf16x4 k0 = *(const bf16x4*)(keysb + (base + 0) * HH + tid * 4);
    bf16x4 k1 = *(const bf16x4*)(keysb + (base + 1) * HH + tid * 4);
    bf16x4 k2 = *(const bf16x4*)(keysb + (base + 2) * HH + tid * 4);
    bf16x4 k3 = *(const bf16x4*)(keysb + (base + 3) * HH + tid * 4);
#pragma unroll
    for (int j = 0; j < 4; ++j) {
      a0[j] += w0 * bf2f(k0[j]);
      a1[j] += w1 * bf2f(k1[j]);
      a2[j] += w2 * bf2f(k2[j]);
      a3[j] += w3 * bf2f(k3[j]);
    }
  }
  f32x4 a = (a0 + a1) + (a2 + a3);
  ((f32x4*)cpart)[(size_t)bc * (HH / 4) + tid] = a;
}

// ---- fp32-keys context partial (fallback path) ----
__global__ void k_ctx_part(const float* __restrict__ keys, const float* __restrict__ wts,
                           float* __restrict__ cpart) {
  int bc = blockIdx.x;
  int b = bc >> 4, sc = bc & 15;
  int tid = threadIdx.x;
  int s0 = sc * 128;
  const f32x4* kv = (const f32x4*)keys;
  f32x4 a0 = {0,0,0,0}, a1 = {0,0,0,0}, a2 = {0,0,0,0}, a3 = {0,0,0,0};
  for (int s = 0; s < 128; s += 4) {
    size_t base = (size_t)b * SS + s0 + s;
    a0 += wts[base + 0] * kv[(base + 0) * (HH / 4) + tid];
    a1 += wts[base + 1] * kv[(base + 1) * (HH / 4) + tid];
    a2 += wts[base + 2] * kv[(base + 2) * (HH / 4) + tid];
    a3 += wts[base + 3] * kv[(base + 3) * (HH / 4) + tid];
  }
  f32x4 a = (a0 + a1) + (a2 + a3);
  ((f32x4*)cpart)[(size_t)bc * (HH / 4) + tid] = a;
}

__global__ void k_ctx_red(const float* __restrict__ cpart, float* __restrict__ ctx) {
  int i = blockIdx.x * 256 + threadIdx.x;  // over B*H
  int b = i >> 10, h = i & 1023;
  float v = 0.f;
#pragma unroll
  for (int sc = 0; sc < 16; ++sc) v += cpart[((size_t)(b * 16 + sc)) * HH + h];
  ctx[i] = v;
}

extern "C" void kernel_launch(void* const* d_in, const int* in_sizes, int n_in,
                              void* d_out, int out_size, void* d_ws, size_t ws_size,
                              hipStream_t stream) {
  (void)in_sizes; (void)n_in; (void)out_size;
  const float* query = (const float*)d_in[0];
  const float* keys  = (const float*)d_in[1];
  const float* wa_w  = (const float*)d_in[2];
  const float* wa_b  = (const float*)d_in[3];
  const float* ua_w  = (const float*)d_in[4];
  const float* ua_b  = (const float*)d_in[5];
  const float* va_w  = (const float*)d_in[6];
  // va_b (d_in[7]) cancels in softmax

  char* ws = (char*)d_ws;
  float* ctx_out = (float*)d_out;            // [32][1024]
  float* w_out   = ctx_out + BB * HH;        // [32][2048]

  const size_t need = (size_t)135 << 20;
  if (ws_size >= need) {
    __bf16* keys_bf = (__bf16*)ws;                              // 128 MB
    __bf16* ua_bf   = (__bf16*)(ws + ((size_t)128 << 20));      // 2 MB
    float*  qpc     = (float*)(ws + ((size_t)130 << 20));       // 128 KB
    float*  spart   = (float*)(ws + ((size_t)131 << 20));       // 2 MB
    float*  cpart   = (float*)(ws + ((size_t)133 << 20));       // 2 MB

    k_convert_keys<<<BB * SS * HH / (256 * 8), 256, 0, stream>>>(keys, keys_bf);
    k_convert_ua<<<1024, 256, 0, stream>>>(ua_w, ua_bf);
    k_qproj<<<1024, 256, 0, stream>>>(query, wa_w, wa_b, ua_b, qpc);
    k_scores5<<<4096, 256, 0, stream>>>(keys_bf, ua_bf, qpc, va_w, spart);
    k_softmax<<<BB, 256, 0, stream>>>(spart, w_out);
    k_ctx_part_bf<<<512, 256, 0, stream>>>(keys_bf, w_out, cpart);
    k_ctx_red<<<BB * HH / 256, 256, 0, stream>>>(cpart, ctx_out);
  } else {
    __bf16* ua_bf  = (__bf16*)ws;                                    // 2 MB
    float*  qpc    = (float*)(ws + (2u << 20));                      // 128 KB
    float*  spart  = (float*)(ws + (2u << 20) + (128u << 10));       // 2 MB
    float*  cpart  = (float*)(ws + (4u << 20) + (128u << 10));       // 2 MB

    k_convert_ua<<<1024, 256, 0, stream>>>(ua_w, ua_bf);
    k_qproj<<<1024, 256, 0, stream>>>(query, wa_w, wa_b, ua_b, qpc);
    k_scores_fused<<<4096, 256, 0, stream>>>(keys, ua_bf, qpc, va_w, spart);
    k_softmax<<<BB, 256, 0, stream>>>(spart, w_out);
    k_ctx_part<<<512, 256, 0, stream>>>(keys, w_out, cpart);
    k_ctx_red<<<BB * HH / 256, 256, 0, stream>>>(cpart, ctx_out);
  }
}